// Round 2
// baseline (192.804 us; speedup 1.0000x reference)
//
#include <hip/hip_runtime.h>
#include <hip/hip_fp16.h>

// Batched trilinear interpolation, 64^3 grid, 96^3 queries, B=8.
// R1: 8 scalar gathers -> 137us. R2: float4 pack -> 105us (L2 thrash).
// R3: XCD-pin + nontemporal -> 82us. R5: fp16 8-corner pack, 1 gather/query,
//     LDS-staged xnew, 2 q/thread -> 53.5us.
// R7: sc0 L1-bypass -> FLAT (53.7). Model: ~3 cyc per divergent line-miss
//     per CU (per-CU miss pipe, L1-agnostic). Floor at 1 miss/query ~= 40us.
// R8: amortize issue overhead: 4 q/thread, mul-by-63, vfloat4 store.
// R9: drop LDS xnew stage (48B/thread directly coalesced as 3x dwordx4),
//     8 q/thread, 8 gathers in flight. FAILED: src addressing double-counted
//     the group offset (3*(t+256g)+768g = 3t+1536g instead of 3t+768g) ->
//     group 1 interpolated at wrong query coords (absmax 4.8).
// R10 (this round): fix src = xb + 3t + 768g. No other change.

#define DIM 64
#define GRID3 (DIM * DIM * DIM)      // 262144 cells per batch
#define MQ (96 * 96 * 96)            // 884736 queries per batch
#define NB 8

typedef float        vfloat4 __attribute__((ext_vector_type(4)));

// ---------------- pack: Q16[b][x][y][z] = 8 corners as fp16 (16B) -------------
// corner order: [v000 v001 v010 v011 v100 v101 v110 v111] (x,y,z bit order)
__global__ __launch_bounds__(256) void pack16_kernel(
    const float* __restrict__ y,     // (B,64,64,64) fp32
    uint4* __restrict__ Q)           // (B,64,64,64) 8xfp16
{
    const int bid = blockIdx.x;
    const int b = bid & 7;                       // XCD-pinned batch
    const int g = (bid >> 3) * 256 + threadIdx.x; // cell-group index (4 cells)
    const int c0 = g << 2;                        // first cell, z4 = c0&63 in {0,4,..,60}
    const int z4 = c0 & 63;
    const int yy = (c0 >> 6) & 63;
    const int x  = c0 >> 12;
    const int yp = (yy + 1 < DIM) ? yy + 1 : yy;
    const int xp = (x  + 1 < DIM) ? x  + 1 : x;
    const int z4n = (z4 + 4 < DIM) ? z4 + 4 : DIM - 1;   // clamped 5th value index

    const float* yb = y + (size_t)b * GRID3;
    const float* r00 = yb + (x  << 12) + (yy << 6);
    const float* r01 = yb + (x  << 12) + (yp << 6);
    const float* r10 = yb + (xp << 12) + (yy << 6);
    const float* r11 = yb + (xp << 12) + (yp << 6);

    // nontemporal: y is read-once here; don't evict the Q lines we're writing.
    vfloat4 a00 = __builtin_nontemporal_load((const vfloat4*)(r00 + z4));
    vfloat4 a01 = __builtin_nontemporal_load((const vfloat4*)(r01 + z4));
    vfloat4 a10 = __builtin_nontemporal_load((const vfloat4*)(r10 + z4));
    vfloat4 a11 = __builtin_nontemporal_load((const vfloat4*)(r11 + z4));
    float e00 = r00[z4n];
    float e01 = r01[z4n];
    float e10 = r10[z4n];
    float e11 = r11[z4n];

    float v00[5] = {a00.x, a00.y, a00.z, a00.w, e00};
    float v01[5] = {a01.x, a01.y, a01.z, a01.w, e01};
    float v10[5] = {a10.x, a10.y, a10.z, a10.w, e10};
    float v11[5] = {a11.x, a11.y, a11.z, a11.w, e11};

    uint4* Qb = Q + (size_t)b * GRID3;
    #pragma unroll
    for (int j = 0; j < 4; ++j) {
        union { __half h[8]; uint4 u; } U;
        U.h[0] = __float2half(v00[j]);     // v000
        U.h[1] = __float2half(v00[j + 1]); // v001
        U.h[2] = __float2half(v01[j]);     // v010
        U.h[3] = __float2half(v01[j + 1]); // v011
        U.h[4] = __float2half(v10[j]);     // v100
        U.h[5] = __float2half(v10[j + 1]); // v101
        U.h[6] = __float2half(v11[j]);     // v110
        U.h[7] = __float2half(v11[j + 1]); // v111
        Qb[c0 + j] = U.u;                  // normal store: keep Q in L2
    }
}

// ---------------- interp: 8 queries/thread, 1 gather per query ----------------
// No LDS: thread t's 4-query group occupies 48 contiguous bytes of xnew
// (3x dwordx4, lane-coalesced). Two groups -> 8 divergent 16B gathers in
// flight before the first lerp consumes any.
__global__ __launch_bounds__(256) void interp3d_q16_kernel(
    const uint4* __restrict__ Q,     // (B,64,64,64) 8xfp16 corners
    const float* __restrict__ xnew,  // (B,M,3)
    float* __restrict__ out)         // (B,M)
{
    const int bid = blockIdx.x;
    const int b = bid & 7;                       // XCD-pinned batch
    const int q0 = (bid >> 3) * 2048;            // first query of this block
    const int t = threadIdx.x;

    const uint4*  Qb = Q + (size_t)b * GRID3;
    const vfloat4* xb = (const vfloat4*)(xnew + ((size_t)b * MQ + q0) * 3);
    float* ob = out + (size_t)b * MQ + q0;

    // ---- group 0: queries 4t..4t+3 ; group 1: queries 1024+4t..1024+4t+3 ----
    float ox[8], oy[8], oz[8];
    const uint4* ap[8];

    #pragma unroll
    for (int g = 0; g < 2; ++g) {
        // group-g queries start at local query 4t + 1024g:
        //   float offset 12t + 3072g  ==  vfloat4 offset 3t + 768g
        const vfloat4* src = xb + 3 * t + 768 * g;
        vfloat4 p0 = __builtin_nontemporal_load(src + 0);
        vfloat4 p1 = __builtin_nontemporal_load(src + 1);
        vfloat4 p2 = __builtin_nontemporal_load(src + 2);
        float f[12] = {p0.x, p0.y, p0.z, p0.w,
                       p1.x, p1.y, p1.z, p1.w,
                       p2.x, p2.y, p2.z, p2.w};
        #pragma unroll
        for (int k = 0; k < 4; ++k) {
            const int s = 4 * g + k;
            // x * 63.0f (vs ref's x / (1/63)): <=1ulp shift; boundary flips are
            // continuous in the interpolant; error stays fp16-pack dominated.
            float rx = f[3 * k + 0] * 63.0f;
            float ry = f[3 * k + 1] * 63.0f;
            float rz = f[3 * k + 2] * 63.0f;
            float fx = floorf(rx), fy = floorf(ry), fz = floorf(rz);
            ox[s] = rx - fx; oy[s] = ry - fy; oz[s] = rz - fz;
            int x0 = (int)fx, y0 = (int)fy, z0 = (int)fz;
            ap[s] = Qb + ((x0 << 12) + (y0 << 6) + z0);
        }
    }

    // ---- 8 independent 16B gathers in flight ----
    uint4 c[8];
    #pragma unroll
    for (int s = 0; s < 8; ++s) c[s] = *ap[s];

    // ---- lerp (reference order: dim0 x, dim1 y, dim2 z) + dense stores ----
    #pragma unroll
    for (int g = 0; g < 2; ++g) {
        float res[4];
        #pragma unroll
        for (int k = 0; k < 4; ++k) {
            const int s = 4 * g + k;
            union { uint4 u; __half h[8]; } U; U.u = c[s];
            float v000 = __half2float(U.h[0]);
            float v001 = __half2float(U.h[1]);
            float v010 = __half2float(U.h[2]);
            float v011 = __half2float(U.h[3]);
            float v100 = __half2float(U.h[4]);
            float v101 = __half2float(U.h[5]);
            float v110 = __half2float(U.h[6]);
            float v111 = __half2float(U.h[7]);

            float w00 = v000 + (v100 - v000) * ox[s];
            float w01 = v001 + (v101 - v001) * ox[s];
            float w10 = v010 + (v110 - v010) * ox[s];
            float w11 = v011 + (v111 - v011) * ox[s];
            float u0 = w00 + (w10 - w00) * oy[s];
            float u1 = w01 + (w11 - w01) * oy[s];
            res[k] = u0 + (u1 - u0) * oz[s];
        }
        vfloat4 r; r.x = res[0]; r.y = res[1]; r.z = res[2]; r.w = res[3];
        __builtin_nontemporal_store(r, (vfloat4*)(ob + 1024 * g + 4 * t));
    }
}

// ---------------- fallback (round-1 kernel) if ws too small -------------------
__global__ __launch_bounds__(256) void interp3d_direct_kernel(
    const float* __restrict__ y,
    const float* __restrict__ xnew,
    float* __restrict__ out)
{
    const int m = blockIdx.x * 256 + threadIdx.x;
    const int b = blockIdx.y;
    const long long idx = (long long)b * MQ + m;

    const float* xp = xnew + idx * 3;
    float qx = xp[0], qy = xp[1], qz = xp[2];

    const float step = 1.0f / 63.0f;
    float rx = qx / step, ry = qy / step, rz = qz / step;
    float fx = floorf(rx), fy = floorf(ry), fz = floorf(rz);
    float ox = rx - fx, oy = ry - fy, oz = rz - fz;

    int x0 = (int)fx, y0 = (int)fy, z0 = (int)fz;
    int x1 = x0 + 1; if (x1 >= DIM) x1 = x0;
    int y1 = y0 + 1; if (y1 >= DIM) y1 = y0;
    int z1 = z0 + 1; if (z1 >= DIM) z1 = z0;

    const float* yb = y + (long long)b * GRID3;
    int bx0 = x0 << 12, bx1 = x1 << 12;
    int by0 = y0 << 6,  by1 = y1 << 6;

    float v000 = yb[bx0 + by0 + z0];
    float v001 = yb[bx0 + by0 + z1];
    float v010 = yb[bx0 + by1 + z0];
    float v011 = yb[bx0 + by1 + z1];
    float v100 = yb[bx1 + by0 + z0];
    float v101 = yb[bx1 + by0 + z1];
    float v110 = yb[bx1 + by1 + z0];
    float v111 = yb[bx1 + by1 + z1];

    float w00 = v000 + (v100 - v000) * ox;
    float w01 = v001 + (v101 - v001) * ox;
    float w10 = v010 + (v110 - v010) * ox;
    float w11 = v011 + (v111 - v011) * ox;

    float u0 = w00 + (w10 - w00) * oy;
    float u1 = w01 + (w11 - w01) * oy;

    out[idx] = u0 + (u1 - u0) * oz;
}

extern "C" void kernel_launch(void* const* d_in, const int* in_sizes, int n_in,
                              void* d_out, int out_size, void* d_ws, size_t ws_size,
                              hipStream_t stream) {
    const float* y    = (const float*)d_in[0];
    const float* xnew = (const float*)d_in[1];
    float* out        = (float*)d_out;

    const size_t need = (size_t)NB * GRID3 * sizeof(uint4);   // 32 MiB
    if (ws_size >= need && (((uintptr_t)d_ws) & 15) == 0) {
        uint4* Q = (uint4*)d_ws;
        pack16_kernel<<<dim3((GRID3 / 4 / 256) * NB), dim3(256), 0, stream>>>(y, Q);
        // 7.08M queries / 2048 per block = 3456 blocks
        interp3d_q16_kernel<<<dim3((MQ / 2048) * NB), dim3(256), 0, stream>>>(Q, xnew, out);
    } else {
        dim3 igrid(MQ / 256, NB);
        interp3d_direct_kernel<<<igrid, dim3(256), 0, stream>>>(y, xnew, out);
    }
}

// Round 3
// 178.638 us; speedup vs baseline: 1.0793x; 1.0793x over previous
//
#include <hip/hip_runtime.h>
#include <hip/hip_fp16.h>

// Batched trilinear interpolation, 64^3 grid, 96^3 queries, B=8.
// R1: 8 scalar gathers -> 137us. R2: float4 pack -> 105us (L2 thrash).
// R3: XCD-pin + nontemporal -> 82us. R5: fp16 8-corner pack, 1 gather/query,
//     LDS-staged xnew, 2 q/thread -> 53.5us.
// R7: sc0 L1-bypass -> FLAT (53.7). Model: ~3 cyc per divergent line-miss
//     per CU (per-CU miss pipe, L1-agnostic). Floor at 1 miss/query ~= 40us.
// R8: amortize issue overhead: 4 q/thread, mul-by-63, vfloat4 store -> 173.7
//     total (interp < 50.5; harness now times ~51us ws-poison fill + ~35us
//     restores per iteration).
// R9/R10: dropped LDS xnew stage, 8 q/thread. REGRESSED: interp 69.5us,
//     VGPR=36 (compiler serialized the 8 gathers), and per-thread 48B reads
//     are stride-48 across the wave (3x TA line-touches on the same per-CU
//     pipe the gathers use). Lesson: LDS stage IS the xnew coalescer.
// R11 (this round): revert to R8 structure (LDS stage, 4 q/thread, 4 gathers
//     in flight) + two 1024-query tiles per block with tile-1 stage issued
//     while tile-0 gathers are in flight (vmcnt in-order => all 7 VMEM ops
//     overlap). Grid 3456 blocks, LDS 12KB.

#define DIM 64
#define GRID3 (DIM * DIM * DIM)      // 262144 cells per batch
#define MQ (96 * 96 * 96)            // 884736 queries per batch
#define NB 8

typedef float        vfloat4 __attribute__((ext_vector_type(4)));

// ---------------- pack: Q16[b][x][y][z] = 8 corners as fp16 (16B) -------------
// corner order: [v000 v001 v010 v011 v100 v101 v110 v111] (x,y,z bit order)
__global__ __launch_bounds__(256) void pack16_kernel(
    const float* __restrict__ y,     // (B,64,64,64) fp32
    uint4* __restrict__ Q)           // (B,64,64,64) 8xfp16
{
    const int bid = blockIdx.x;
    const int b = bid & 7;                       // XCD-pinned batch
    const int g = (bid >> 3) * 256 + threadIdx.x; // cell-group index (4 cells)
    const int c0 = g << 2;                        // first cell, z4 = c0&63 in {0,4,..,60}
    const int z4 = c0 & 63;
    const int yy = (c0 >> 6) & 63;
    const int x  = c0 >> 12;
    const int yp = (yy + 1 < DIM) ? yy + 1 : yy;
    const int xp = (x  + 1 < DIM) ? x  + 1 : x;
    const int z4n = (z4 + 4 < DIM) ? z4 + 4 : DIM - 1;   // clamped 5th value index

    const float* yb = y + (size_t)b * GRID3;
    const float* r00 = yb + (x  << 12) + (yy << 6);
    const float* r01 = yb + (x  << 12) + (yp << 6);
    const float* r10 = yb + (xp << 12) + (yy << 6);
    const float* r11 = yb + (xp << 12) + (yp << 6);

    // nontemporal: y is read-once here; don't evict the Q lines we're writing.
    vfloat4 a00 = __builtin_nontemporal_load((const vfloat4*)(r00 + z4));
    vfloat4 a01 = __builtin_nontemporal_load((const vfloat4*)(r01 + z4));
    vfloat4 a10 = __builtin_nontemporal_load((const vfloat4*)(r10 + z4));
    vfloat4 a11 = __builtin_nontemporal_load((const vfloat4*)(r11 + z4));
    float e00 = r00[z4n];
    float e01 = r01[z4n];
    float e10 = r10[z4n];
    float e11 = r11[z4n];

    float v00[5] = {a00.x, a00.y, a00.z, a00.w, e00};
    float v01[5] = {a01.x, a01.y, a01.z, a01.w, e01};
    float v10[5] = {a10.x, a10.y, a10.z, a10.w, e10};
    float v11[5] = {a11.x, a11.y, a11.z, a11.w, e11};

    uint4* Qb = Q + (size_t)b * GRID3;
    #pragma unroll
    for (int j = 0; j < 4; ++j) {
        union { __half h[8]; uint4 u; } U;
        U.h[0] = __float2half(v00[j]);     // v000
        U.h[1] = __float2half(v00[j + 1]); // v001
        U.h[2] = __float2half(v01[j]);     // v010
        U.h[3] = __float2half(v01[j + 1]); // v011
        U.h[4] = __float2half(v10[j]);     // v100
        U.h[5] = __float2half(v10[j + 1]); // v101
        U.h[6] = __float2half(v11[j]);     // v110
        U.h[7] = __float2half(v11[j + 1]); // v111
        Qb[c0 + j] = U.u;                  // normal store: keep Q in L2
    }
}

// ---------------- 8-corner fp16 lerp (reference order: x, y, z) --------------
__device__ __forceinline__ float lerp8(uint4 c, float ox, float oy, float oz) {
    union { uint4 u; __half h[8]; } U; U.u = c;
    float v000 = __half2float(U.h[0]);
    float v001 = __half2float(U.h[1]);
    float v010 = __half2float(U.h[2]);
    float v011 = __half2float(U.h[3]);
    float v100 = __half2float(U.h[4]);
    float v101 = __half2float(U.h[5]);
    float v110 = __half2float(U.h[6]);
    float v111 = __half2float(U.h[7]);

    float w00 = v000 + (v100 - v000) * ox;
    float w01 = v001 + (v101 - v001) * ox;
    float w10 = v010 + (v110 - v010) * ox;
    float w11 = v011 + (v111 - v011) * ox;
    float u0 = w00 + (w10 - w00) * oy;
    float u1 = w01 + (w11 - w01) * oy;
    return u0 + (u1 - u0) * oz;
}

// ---------------- interp: 2 tiles x 1024 queries per block -------------------
// LDS-staged xnew (dense wave-coalesced float4 loads), 4 q/thread per tile,
// 4 divergent 16B gathers in flight; tile-1 stage overlapped with tile-0
// gathers (in-order vmcnt keeps all 7 VMEM ops in flight together).
__global__ __launch_bounds__(256) void interp3d_q16_kernel(
    const uint4* __restrict__ Q,     // (B,64,64,64) 8xfp16 corners
    const float* __restrict__ xnew,  // (B,M,3)
    float* __restrict__ out)         // (B,M)
{
    __shared__ vfloat4 ls4[768];                 // 1024 queries * 3 floats = 12KB
    float* lsf = (float*)ls4;

    const int bid = blockIdx.x;
    const int b = bid & 7;                       // XCD-pinned batch
    const int q0 = (bid >> 3) * 2048;            // first query of this block
    const int t = threadIdx.x;

    const uint4*   Qb = Q + (size_t)b * GRID3;
    const vfloat4* xb = (const vfloat4*)(xnew + ((size_t)b * MQ + q0) * 3);
    float*         ob = out + (size_t)b * MQ + q0;

    // ---- stage tile 0 (dense, nontemporal) ----
    #pragma unroll
    for (int j = 0; j < 3; ++j)
        ls4[t + 256 * j] = __builtin_nontemporal_load(xb + t + 256 * j);
    __syncthreads();

    // ---- tile-0 offsets + cell pointers (4 queries: 4t..4t+3) ----
    float ox0[4], oy0[4], oz0[4];
    const uint4* ap0[4];
    #pragma unroll
    for (int k = 0; k < 4; ++k) {
        const int lq = 4 * t + k;
        // x * 63.0f (vs ref's x / (1/63)): <=1ulp shift; boundary flips are
        // continuous in the interpolant; error stays fp16-pack dominated.
        float rx = lsf[3 * lq + 0] * 63.0f;
        float ry = lsf[3 * lq + 1] * 63.0f;
        float rz = lsf[3 * lq + 2] * 63.0f;
        float fx = floorf(rx), fy = floorf(ry), fz = floorf(rz);
        ox0[k] = rx - fx; oy0[k] = ry - fy; oz0[k] = rz - fz;
        ap0[k] = Qb + (((int)fx << 12) + ((int)fy << 6) + (int)fz);
    }
    __syncthreads();                             // LDS tile 0 fully consumed

    // ---- tile-0 gathers, then tile-1 stage issued behind them ----
    uint4 c0[4];
    #pragma unroll
    for (int k = 0; k < 4; ++k) c0[k] = *ap0[k];
    #pragma unroll
    for (int j = 0; j < 3; ++j)
        ls4[t + 256 * j] = __builtin_nontemporal_load(xb + 768 + t + 256 * j);

    // ---- tile-0 lerp + dense store ----
    {
        vfloat4 r;
        r.x = lerp8(c0[0], ox0[0], oy0[0], oz0[0]);
        r.y = lerp8(c0[1], ox0[1], oy0[1], oz0[1]);
        r.z = lerp8(c0[2], ox0[2], oy0[2], oz0[2]);
        r.w = lerp8(c0[3], ox0[3], oy0[3], oz0[3]);
        __builtin_nontemporal_store(r, (vfloat4*)(ob + 4 * t));
    }
    __syncthreads();                             // stage-1 LDS writes visible

    // ---- tile-1 offsets + gathers + lerp + store ----
    float ox1[4], oy1[4], oz1[4];
    const uint4* ap1[4];
    #pragma unroll
    for (int k = 0; k < 4; ++k) {
        const int lq = 4 * t + k;
        float rx = lsf[3 * lq + 0] * 63.0f;
        float ry = lsf[3 * lq + 1] * 63.0f;
        float rz = lsf[3 * lq + 2] * 63.0f;
        float fx = floorf(rx), fy = floorf(ry), fz = floorf(rz);
        ox1[k] = rx - fx; oy1[k] = ry - fy; oz1[k] = rz - fz;
        ap1[k] = Qb + (((int)fx << 12) + ((int)fy << 6) + (int)fz);
    }
    uint4 c1[4];
    #pragma unroll
    for (int k = 0; k < 4; ++k) c1[k] = *ap1[k];
    {
        vfloat4 r;
        r.x = lerp8(c1[0], ox1[0], oy1[0], oz1[0]);
        r.y = lerp8(c1[1], ox1[1], oy1[1], oz1[1]);
        r.z = lerp8(c1[2], ox1[2], oy1[2], oz1[2]);
        r.w = lerp8(c1[3], ox1[3], oy1[3], oz1[3]);
        __builtin_nontemporal_store(r, (vfloat4*)(ob + 1024 + 4 * t));
    }
}

// ---------------- fallback (round-1 kernel) if ws too small -------------------
__global__ __launch_bounds__(256) void interp3d_direct_kernel(
    const float* __restrict__ y,
    const float* __restrict__ xnew,
    float* __restrict__ out)
{
    const int m = blockIdx.x * 256 + threadIdx.x;
    const int b = blockIdx.y;
    const long long idx = (long long)b * MQ + m;

    const float* xp = xnew + idx * 3;
    float qx = xp[0], qy = xp[1], qz = xp[2];

    const float step = 1.0f / 63.0f;
    float rx = qx / step, ry = qy / step, rz = qz / step;
    float fx = floorf(rx), fy = floorf(ry), fz = floorf(rz);
    float ox = rx - fx, oy = ry - fy, oz = rz - fz;

    int x0 = (int)fx, y0 = (int)fy, z0 = (int)fz;
    int x1 = x0 + 1; if (x1 >= DIM) x1 = x0;
    int y1 = y0 + 1; if (y1 >= DIM) y1 = y0;
    int z1 = z0 + 1; if (z1 >= DIM) z1 = z0;

    const float* yb = y + (long long)b * GRID3;
    int bx0 = x0 << 12, bx1 = x1 << 12;
    int by0 = y0 << 6,  by1 = y1 << 6;

    float v000 = yb[bx0 + by0 + z0];
    float v001 = yb[bx0 + by0 + z1];
    float v010 = yb[bx0 + by1 + z0];
    float v011 = yb[bx0 + by1 + z1];
    float v100 = yb[bx1 + by0 + z0];
    float v101 = yb[bx1 + by0 + z1];
    float v110 = yb[bx1 + by1 + z0];
    float v111 = yb[bx1 + by1 + z1];

    float w00 = v000 + (v100 - v000) * ox;
    float w01 = v001 + (v101 - v001) * ox;
    float w10 = v010 + (v110 - v010) * ox;
    float w11 = v011 + (v111 - v011) * ox;

    float u0 = w00 + (w10 - w00) * oy;
    float u1 = w01 + (w11 - w01) * oy;

    out[idx] = u0 + (u1 - u0) * oz;
}

extern "C" void kernel_launch(void* const* d_in, const int* in_sizes, int n_in,
                              void* d_out, int out_size, void* d_ws, size_t ws_size,
                              hipStream_t stream) {
    const float* y    = (const float*)d_in[0];
    const float* xnew = (const float*)d_in[1];
    float* out        = (float*)d_out;

    const size_t need = (size_t)NB * GRID3 * sizeof(uint4);   // 32 MiB
    if (ws_size >= need && (((uintptr_t)d_ws) & 15) == 0) {
        uint4* Q = (uint4*)d_ws;
        pack16_kernel<<<dim3((GRID3 / 4 / 256) * NB), dim3(256), 0, stream>>>(y, Q);
        // 7.08M queries / 2048 per block = 3456 blocks
        interp3d_q16_kernel<<<dim3((MQ / 2048) * NB), dim3(256), 0, stream>>>(Q, xnew, out);
    } else {
        dim3 igrid(MQ / 256, NB);
        interp3d_direct_kernel<<<igrid, dim3(256), 0, stream>>>(y, xnew, out);
    }
}

// Round 4
// 174.191 us; speedup vs baseline: 1.1069x; 1.0255x over previous
//
#include <hip/hip_runtime.h>
#include <hip/hip_fp16.h>

// Batched trilinear interpolation, 64^3 grid, 96^3 queries, B=8.
// R1: 8 scalar gathers -> 137us. R2: float4 pack -> 105us (L2 thrash).
// R3: XCD-pin + nontemporal -> 82us. R5: fp16 8-corner pack, 1 gather/query,
//     LDS-staged xnew, 2 q/thread -> 53.5us.
// R7: sc0 L1-bypass -> FLAT. Model: ~3 cyc per divergent line-miss per CU
//     (per-CU miss pipe, L1-agnostic). Floor at 1 miss/query ~= 40us interp.
// R8: 4 q/thread, mul-by-63, vfloat4 store -> 173.7 total (interp < 50.5;
//     harness times ~51us ws-poison fill + restores each iteration).
// R9/R10: no-LDS 8 q/thread REGRESSED (69.5us): VGPR=36 = compiler serialized
//     gathers; per-thread 48B xnew reads = 3x TA line-touches. LDS stage IS
//     the xnew coalescer.
// R11: 2-tile overlap REGRESSED (55.3us): VGPR=32 again (no forced MLP),
//     3 barriers, 8-way LDS bank conflict (442K cyc) from stride-12 reads.
// R12 (this round): single stage of 2048 q (24KB LDS), ONE barrier, 8
//     q/thread STRIDED (lq = t+256k): LDS reads at 3t+768k hit all 32 banks
//     (gcd(3,32)=1, 2 lanes/bank = free); sched_barrier(0) between the 8
//     gather issues and first lerp FORCES 8-deep MLP (compiler must hold 8
//     uint4 live). Expect VGPR ~80, interp ~45-48us.

#define DIM 64
#define GRID3 (DIM * DIM * DIM)      // 262144 cells per batch
#define MQ (96 * 96 * 96)            // 884736 queries per batch
#define NB 8

typedef float        vfloat4 __attribute__((ext_vector_type(4)));

// ---------------- pack: Q16[b][x][y][z] = 8 corners as fp16 (16B) -------------
// corner order: [v000 v001 v010 v011 v100 v101 v110 v111] (x,y,z bit order)
__global__ __launch_bounds__(256) void pack16_kernel(
    const float* __restrict__ y,     // (B,64,64,64) fp32
    uint4* __restrict__ Q)           // (B,64,64,64) 8xfp16
{
    const int bid = blockIdx.x;
    const int b = bid & 7;                       // XCD-pinned batch
    const int g = (bid >> 3) * 256 + threadIdx.x; // cell-group index (4 cells)
    const int c0 = g << 2;                        // first cell, z4 = c0&63 in {0,4,..,60}
    const int z4 = c0 & 63;
    const int yy = (c0 >> 6) & 63;
    const int x  = c0 >> 12;
    const int yp = (yy + 1 < DIM) ? yy + 1 : yy;
    const int xp = (x  + 1 < DIM) ? x  + 1 : x;
    const int z4n = (z4 + 4 < DIM) ? z4 + 4 : DIM - 1;   // clamped 5th value index

    const float* yb = y + (size_t)b * GRID3;
    const float* r00 = yb + (x  << 12) + (yy << 6);
    const float* r01 = yb + (x  << 12) + (yp << 6);
    const float* r10 = yb + (xp << 12) + (yy << 6);
    const float* r11 = yb + (xp << 12) + (yp << 6);

    // nontemporal: y is read-once here; don't evict the Q lines we're writing.
    vfloat4 a00 = __builtin_nontemporal_load((const vfloat4*)(r00 + z4));
    vfloat4 a01 = __builtin_nontemporal_load((const vfloat4*)(r01 + z4));
    vfloat4 a10 = __builtin_nontemporal_load((const vfloat4*)(r10 + z4));
    vfloat4 a11 = __builtin_nontemporal_load((const vfloat4*)(r11 + z4));
    float e00 = r00[z4n];
    float e01 = r01[z4n];
    float e10 = r10[z4n];
    float e11 = r11[z4n];

    float v00[5] = {a00.x, a00.y, a00.z, a00.w, e00};
    float v01[5] = {a01.x, a01.y, a01.z, a01.w, e01};
    float v10[5] = {a10.x, a10.y, a10.z, a10.w, e10};
    float v11[5] = {a11.x, a11.y, a11.z, a11.w, e11};

    uint4* Qb = Q + (size_t)b * GRID3;
    #pragma unroll
    for (int j = 0; j < 4; ++j) {
        union { __half h[8]; uint4 u; } U;
        U.h[0] = __float2half(v00[j]);     // v000
        U.h[1] = __float2half(v00[j + 1]); // v001
        U.h[2] = __float2half(v01[j]);     // v010
        U.h[3] = __float2half(v01[j + 1]); // v011
        U.h[4] = __float2half(v10[j]);     // v100
        U.h[5] = __float2half(v10[j + 1]); // v101
        U.h[6] = __float2half(v11[j]);     // v110
        U.h[7] = __float2half(v11[j + 1]); // v111
        Qb[c0 + j] = U.u;                  // normal store: keep Q in L2
    }
}

// ---------------- 8-corner fp16 lerp (reference order: x, y, z) --------------
__device__ __forceinline__ float lerp8(uint4 c, float ox, float oy, float oz) {
    union { uint4 u; __half h[8]; } U; U.u = c;
    float v000 = __half2float(U.h[0]);
    float v001 = __half2float(U.h[1]);
    float v010 = __half2float(U.h[2]);
    float v011 = __half2float(U.h[3]);
    float v100 = __half2float(U.h[4]);
    float v101 = __half2float(U.h[5]);
    float v110 = __half2float(U.h[6]);
    float v111 = __half2float(U.h[7]);

    float w00 = v000 + (v100 - v000) * ox;
    float w01 = v001 + (v101 - v001) * ox;
    float w10 = v010 + (v110 - v010) * ox;
    float w11 = v011 + (v111 - v011) * ox;
    float u0 = w00 + (w10 - w00) * oy;
    float u1 = w01 + (w11 - w01) * oy;
    return u0 + (u1 - u0) * oz;
}

// ---------------- interp: 2048 queries/block, 8 q/thread (strided) -----------
// One LDS stage (24KB, dense wave-coalesced float4), ONE barrier, 8 divergent
// 16B gathers forced in flight via sched_barrier(0), strided dword stores.
__global__ __launch_bounds__(256) void interp3d_q16_kernel(
    const uint4* __restrict__ Q,     // (B,64,64,64) 8xfp16 corners
    const float* __restrict__ xnew,  // (B,M,3)
    float* __restrict__ out)         // (B,M)
{
    __shared__ vfloat4 ls4[1536];                // 2048 queries * 3 floats = 24KB
    float* lsf = (float*)ls4;

    const int bid = blockIdx.x;
    const int b = bid & 7;                       // XCD-pinned batch
    const int q0 = (bid >> 3) * 2048;            // first query of this block
    const int t = threadIdx.x;

    const uint4*   Qb = Q + (size_t)b * GRID3;
    const vfloat4* xb = (const vfloat4*)(xnew + ((size_t)b * MQ + q0) * 3);
    float*         ob = out + (size_t)b * MQ + q0;

    // ---- stage 2048 queries (dense, nontemporal) ----
    #pragma unroll
    for (int j = 0; j < 6; ++j)
        ls4[t + 256 * j] = __builtin_nontemporal_load(xb + t + 256 * j);
    __syncthreads();

    // ---- offsets + cell pointers for 8 strided queries (lq = t + 256k) ----
    // LDS read addr = 3t + 768k words: gcd(3,32)=1 -> all 32 banks, 2/bank.
    float ox[8], oy[8], oz[8];
    const uint4* ap[8];
    #pragma unroll
    for (int k = 0; k < 8; ++k) {
        const int base = 3 * t + 768 * k;
        // x * 63.0f (vs ref's x / (1/63)): <=1ulp shift; boundary flips are
        // continuous in the interpolant; error stays fp16-pack dominated.
        float rx = lsf[base + 0] * 63.0f;
        float ry = lsf[base + 1] * 63.0f;
        float rz = lsf[base + 2] * 63.0f;
        float fx = floorf(rx), fy = floorf(ry), fz = floorf(rz);
        ox[k] = rx - fx; oy[k] = ry - fy; oz[k] = rz - fz;
        ap[k] = Qb + (((int)fx << 12) + ((int)fy << 6) + (int)fz);
    }

    // ---- 8 independent 16B gathers; sched_barrier pins them all in flight ----
    uint4 c[8];
    #pragma unroll
    for (int k = 0; k < 8; ++k) c[k] = *ap[k];
    __builtin_amdgcn_sched_barrier(0);           // no lerp may move above here

    // ---- lerp + strided dense dword stores ----
    #pragma unroll
    for (int k = 0; k < 8; ++k) {
        float r = lerp8(c[k], ox[k], oy[k], oz[k]);
        __builtin_nontemporal_store(r, ob + t + 256 * k);
    }
}

// ---------------- fallback (round-1 kernel) if ws too small -------------------
__global__ __launch_bounds__(256) void interp3d_direct_kernel(
    const float* __restrict__ y,
    const float* __restrict__ xnew,
    float* __restrict__ out)
{
    const int m = blockIdx.x * 256 + threadIdx.x;
    const int b = blockIdx.y;
    const long long idx = (long long)b * MQ + m;

    const float* xp = xnew + idx * 3;
    float qx = xp[0], qy = xp[1], qz = xp[2];

    const float step = 1.0f / 63.0f;
    float rx = qx / step, ry = qy / step, rz = qz / step;
    float fx = floorf(rx), fy = floorf(ry), fz = floorf(rz);
    float ox = rx - fx, oy = ry - fy, oz = rz - fz;

    int x0 = (int)fx, y0 = (int)fy, z0 = (int)fz;
    int x1 = x0 + 1; if (x1 >= DIM) x1 = x0;
    int y1 = y0 + 1; if (y1 >= DIM) y1 = y0;
    int z1 = z0 + 1; if (z1 >= DIM) z1 = z0;

    const float* yb = y + (long long)b * GRID3;
    int bx0 = x0 << 12, bx1 = x1 << 12;
    int by0 = y0 << 6,  by1 = y1 << 6;

    float v000 = yb[bx0 + by0 + z0];
    float v001 = yb[bx0 + by0 + z1];
    float v010 = yb[bx0 + by1 + z0];
    float v011 = yb[bx0 + by1 + z1];
    float v100 = yb[bx1 + by0 + z0];
    float v101 = yb[bx1 + by0 + z1];
    float v110 = yb[bx1 + by1 + z0];
    float v111 = yb[bx1 + by1 + z1];

    float w00 = v000 + (v100 - v000) * ox;
    float w01 = v001 + (v101 - v001) * ox;
    float w10 = v010 + (v110 - v010) * ox;
    float w11 = v011 + (v111 - v011) * ox;

    float u0 = w00 + (w10 - w00) * oy;
    float u1 = w01 + (w11 - w01) * oy;

    out[idx] = u0 + (u1 - u0) * oz;
}

extern "C" void kernel_launch(void* const* d_in, const int* in_sizes, int n_in,
                              void* d_out, int out_size, void* d_ws, size_t ws_size,
                              hipStream_t stream) {
    const float* y    = (const float*)d_in[0];
    const float* xnew = (const float*)d_in[1];
    float* out        = (float*)d_out;

    const size_t need = (size_t)NB * GRID3 * sizeof(uint4);   // 32 MiB
    if (ws_size >= need && (((uintptr_t)d_ws) & 15) == 0) {
        uint4* Q = (uint4*)d_ws;
        pack16_kernel<<<dim3((GRID3 / 4 / 256) * NB), dim3(256), 0, stream>>>(y, Q);
        // 7.08M queries / 2048 per block = 3456 blocks
        interp3d_q16_kernel<<<dim3((MQ / 2048) * NB), dim3(256), 0, stream>>>(Q, xnew, out);
    } else {
        dim3 igrid(MQ / 256, NB);
        interp3d_direct_kernel<<<igrid, dim3(256), 0, stream>>>(y, xnew, out);
    }
}